// Round 1
// 602.037 us; speedup vs baseline: 1.0895x; 1.0895x over previous
//
#include <hip/hip_runtime.h>
#include <hip/hip_bf16.h>
#include <cstdint>
#include <cstddef>

// HierarchicalAttention on MI355X (gfx950).
// R3 change: both GEMMs ported from the m97 128^2 2-barrier structure (669 TF,
// MfmaUtil 30%) to the 256^2 / BK=64 / 8-wave 8-phase schedule with counted
// vmcnt (T3+T4), LDS XOR-swizzle (T2), setprio around MFMA (T5), XCD-chunked
// block swizzle (T1). Staging schedule (derived, race-free by construction):
//   tile t phases p0..p3 compute quadrants (mh,nh) = (0,0),(0,1),(1,0),(1,1)
//   p0: stage A(t+1) chunks {0,2} -> buf[(t+1)&1]   (other buffer: safe)
//   p1: stage A(t+1) chunks {1,3}
//   p2: stage B(t+2) chunks {0,1} -> buf[t&1]       (B-reads of tile t done @p1)
//   p3: stage B(t+2) chunks {2,3}; s_waitcnt vmcnt(4)  <- only wait, 4 loads
//       stay in flight across the tile boundary (never drain to 0)
//
// Workspace layout (total 343,932,928 B):
//   [0)            x_bf16     [32768,1024]  67,108,864 B
//   [67108864)     wqkv_bf16  [3072,1024]    6,291,456 B
//   [73400320)     wproj_bf16 [1024,1024]    2,097,152 B
//   [75497472)     qkv_bf16   [32768,3072] 201,326,592 B
//   [276824064)    attn_bf16  [32768,1024]  67,108,864 B

typedef __attribute__((ext_vector_type(8))) short short8;
typedef __attribute__((ext_vector_type(4))) float float4v;

static __device__ __forceinline__ void async16(void* lds_p, const void* g) {
  // global -> LDS direct copy, 16B per lane; LDS dest = wave-uniform base + lane*16
  __builtin_amdgcn_global_load_lds((const __attribute__((address_space(1))) void*)g,
                                   (__attribute__((address_space(3))) void*)lds_p,
                                   16, 0, 0);
}

static __device__ __forceinline__ unsigned short f2bf_bits(float x) {
  unsigned int u = __float_as_uint(x);
  unsigned int r = (u + 0x7fffu + ((u >> 16) & 1u)) >> 16;  // RNE
  return (unsigned short)r;
}

#define S_BARRIER() asm volatile("s_barrier" ::: "memory")
#define WAIT_VM(n)  asm volatile("s_waitcnt vmcnt(" #n ")" ::: "memory")

// ---------------- cast fp32 -> bf16 (vectorized) ---------------------------
__global__ __launch_bounds__(256) void cast_f32_to_bf16(
    const float* __restrict__ in, unsigned short* __restrict__ out, int n4) {
  int i = blockIdx.x * 256 + threadIdx.x;
  if (i >= n4) return;
  float4 v = ((const float4*)in)[i];
  ushort4 o;
  o.x = f2bf_bits(v.x); o.y = f2bf_bits(v.y);
  o.z = f2bf_bits(v.z); o.w = f2bf_bits(v.w);
  ((ushort4*)out)[i] = o;
}

// ---------------- GEMM: C[M,N] = A[M,K] * B[N,K]^T + bias ------------------
// 256x256 tile, BK=64, 8 waves (2Mx4N), per-wave 128x64 output = acc[8][4]
// of mfma_f32_16x16x32_bf16 fragments. LDS 128 KiB: A[2][256][64] B[2][256][64]
// bf16, group-XOR swizzled: slot (row, g) holds global col-group g^(row&7)
// (involution; applied on the pre-swizzled global source since global_load_lds
// writes linearly, and on the ds_read address — rule 21 both-sides).
// M,N divisible by 256 (mtiles div by 8), K divisible by 64; no bounds checks.
template<bool OUT_BF16>
__global__ __launch_bounds__(512, 2) void gemm256(
    const unsigned short* __restrict__ A,   // [M,K] bf16 bits
    const unsigned short* __restrict__ B,   // [N,K] bf16 bits
    const float* __restrict__ bias,         // [N]
    void* __restrict__ Cout,                // [M,N] bf16 or fp32
    int M, int N, int K, int ntiles)
{
  extern __shared__ unsigned short lds[];
  // elems: A buf0 [0,16384) buf1 [16384,32768); B buf0 [32768,49152) buf1 [49152,65536)

  const int t    = threadIdx.x;             // 0..511
  const int wave = t >> 6;
  const int lane = t & 63;
  const int lr   = lane & 15;
  const int lq   = lane >> 4;
  const int wm   = wave >> 2;               // 0..1
  const int wn   = wave & 3;                // 0..3

  // T1: XCD-chunked swizzle (grid % 8 == 0), then GROUP_M=8 (bm-fast inner)
  const int nwg  = gridDim.x;
  const int q8   = nwg >> 3;
  const int wg   = ((int)blockIdx.x & 7) * q8 + ((int)blockIdx.x >> 3);
  const int GM   = 8;
  const int group = wg / (GM * ntiles);
  const int inG   = wg % (GM * ntiles);
  const int bm    = group * GM + (inG % GM);
  const int bn    = inG / GM;

  // staging: thread t covers LDS elems [chunk + t*8, +8); chunk = 64 rows x 64 cols
  // source col-group pre-swizzled by row&7 so the linear LDS write lands swizzled
  const int srow = t >> 3;                            // 0..63 within chunk
  const int sswz = ((t & 7) ^ (srow & 7)) << 3;       // swizzled col (elems)
  const unsigned short* Abase = A + (size_t)(bm * 256 + srow) * K + sswz;
  const unsigned short* Bbase = B + (size_t)(bn * 256 + srow) * K + sswz;
  const int ldsw = wave * 512;                        // wave-uniform stage base (elems)

  auto stageA = [&](int kt, int c) {
    async16(lds + (kt & 1) * 16384 + c * 4096 + ldsw,
            Abase + (size_t)(c * 64) * K + kt * 64);
  };
  auto stageB = [&](int kt, int c) {
    async16(lds + 32768 + (kt & 1) * 16384 + c * 4096 + ldsw,
            Bbase + (size_t)(c * 64) * K + kt * 64);
  };

  // frag-read swizzled k-group offsets (elems); row&7 == lr&7 for all frags
  const int g0 = ((0 + lq) ^ (lr & 7)) << 3;          // ks=0 -> k = lq*8
  const int g1 = ((4 + lq) ^ (lr & 7)) << 3;          // ks=1 -> k = 32+lq*8
  const int arow0 = (wm * 128 + lr) * 64;             // + mf*1024
  const int brow0 = (wn * 64 + lr) * 64;              // + nf*1024

  float4v acc[8][4];
  #pragma unroll
  for (int i = 0; i < 8; ++i)
    #pragma unroll
    for (int j = 0; j < 4; ++j) acc[i][j] = (float4v){0.f, 0.f, 0.f, 0.f};

  const int NT = K >> 6;                              // 16 for K=1024

  // prologue: B(0), A(0), B(1) staged (12 loads); keep B(1)'s 4 in flight
  #pragma unroll
  for (int c = 0; c < 4; ++c) stageB(0, c);
  #pragma unroll
  for (int c = 0; c < 4; ++c) stageA(0, c);
  #pragma unroll
  for (int c = 0; c < 4; ++c) stageB(1, c);
  WAIT_VM(4);
  S_BARRIER();

  short8 af[4][2], bf[2][2], bf2[2][2];

  for (int kt = 0; kt < NT; ++kt) {
    const int bc = kt & 1;
    int kt1 = kt + 1; if (kt1 == NT) kt1 = 0;         // wrapped stages are
    int kt2 = kt + 2; if (kt2 >= NT) kt2 -= NT;       // harmless (never read)
    const unsigned short* Al = lds + bc * 16384;
    const unsigned short* Bl = lds + 32768 + bc * 16384;

    // ---- phase 0: read A(mh0) + B(nh0); stage A(kt1){0,2}; MFMA q(0,0) ----
    #pragma unroll
    for (int mf = 0; mf < 4; ++mf) {
      af[mf][0] = *(const short8*)(Al + arow0 + mf * 1024 + g0);
      af[mf][1] = *(const short8*)(Al + arow0 + mf * 1024 + g1);
    }
    #pragma unroll
    for (int nf = 0; nf < 2; ++nf) {
      bf[nf][0] = *(const short8*)(Bl + brow0 + nf * 1024 + g0);
      bf[nf][1] = *(const short8*)(Bl + brow0 + nf * 1024 + g1);
    }
    stageA(kt1, 0); stageA(kt1, 2);
    S_BARRIER();
    __builtin_amdgcn_s_setprio(1);
    #pragma unroll
    for (int mf = 0; mf < 4; ++mf)
      #pragma unroll
      for (int nf = 0; nf < 2; ++nf) {
        acc[mf][nf] = __builtin_amdgcn_mfma_f32_16x16x32_bf16(af[mf][0], bf[nf][0], acc[mf][nf], 0, 0, 0);
        acc[mf][nf] = __builtin_amdgcn_mfma_f32_16x16x32_bf16(af[mf][1], bf[nf][1], acc[mf][nf], 0, 0, 0);
      }
    __builtin_amdgcn_s_setprio(0);
    S_BARRIER();

    // ---- phase 1: read B(nh1); stage A(kt1){1,3}; MFMA q(0,1) -------------
    #pragma unroll
    for (int nf = 0; nf < 2; ++nf) {
      bf2[nf][0] = *(const short8*)(Bl + brow0 + (2 + nf) * 1024 + g0);
      bf2[nf][1] = *(const short8*)(Bl + brow0 + (2 + nf) * 1024 + g1);
    }
    stageA(kt1, 1); stageA(kt1, 3);
    S_BARRIER();
    __builtin_amdgcn_s_setprio(1);
    #pragma unroll
    for (int mf = 0; mf < 4; ++mf)
      #pragma unroll
      for (int nf = 0; nf < 2; ++nf) {
        acc[mf][2 + nf] = __builtin_amdgcn_mfma_f32_16x16x32_bf16(af[mf][0], bf2[nf][0], acc[mf][2 + nf], 0, 0, 0);
        acc[mf][2 + nf] = __builtin_amdgcn_mfma_f32_16x16x32_bf16(af[mf][1], bf2[nf][1], acc[mf][2 + nf], 0, 0, 0);
      }
    __builtin_amdgcn_s_setprio(0);
    S_BARRIER();

    // ---- phase 2: read A(mh1); stage B(kt2){0,1}; MFMA q(1,0) -------------
    #pragma unroll
    for (int mf = 0; mf < 4; ++mf) {
      af[mf][0] = *(const short8*)(Al + arow0 + (4 + mf) * 1024 + g0);
      af[mf][1] = *(const short8*)(Al + arow0 + (4 + mf) * 1024 + g1);
    }
    stageB(kt2, 0); stageB(kt2, 1);
    S_BARRIER();
    __builtin_amdgcn_s_setprio(1);
    #pragma unroll
    for (int mf = 0; mf < 4; ++mf)
      #pragma unroll
      for (int nf = 0; nf < 2; ++nf) {
        acc[4 + mf][nf] = __builtin_amdgcn_mfma_f32_16x16x32_bf16(af[mf][0], bf[nf][0], acc[4 + mf][nf], 0, 0, 0);
        acc[4 + mf][nf] = __builtin_amdgcn_mfma_f32_16x16x32_bf16(af[mf][1], bf[nf][1], acc[4 + mf][nf], 0, 0, 0);
      }
    __builtin_amdgcn_s_setprio(0);
    S_BARRIER();

    // ---- phase 3: stage B(kt2){2,3}; vmcnt(4) [A(kt1)+B(kt1) landed,
    //      B(kt2) stays in flight]; MFMA q(1,1) ----------------------------
    stageB(kt2, 2); stageB(kt2, 3);
    WAIT_VM(4);
    S_BARRIER();
    __builtin_amdgcn_s_setprio(1);
    #pragma unroll
    for (int mf = 0; mf < 4; ++mf)
      #pragma unroll
      for (int nf = 0; nf < 2; ++nf) {
        acc[4 + mf][2 + nf] = __builtin_amdgcn_mfma_f32_16x16x32_bf16(af[mf][0], bf2[nf][0], acc[4 + mf][2 + nf], 0, 0, 0);
        acc[4 + mf][2 + nf] = __builtin_amdgcn_mfma_f32_16x16x32_bf16(af[mf][1], bf2[nf][1], acc[4 + mf][2 + nf], 0, 0, 0);
      }
    __builtin_amdgcn_s_setprio(0);
    S_BARRIER();
  }

  // epilogue: C/D layout col=lane&15, row=(lane>>4)*4+reg (m89-verified)
  const int rbase = bm * 256 + wm * 128 + lq * 4;
  const int cbase = bn * 256 + wn * 64 + lr;
  #pragma unroll
  for (int nf = 0; nf < 4; ++nf) {
    const int col = cbase + nf * 16;
    const float bv = bias[col];
    #pragma unroll
    for (int mf = 0; mf < 8; ++mf) {
      const int row = rbase + mf * 16;
      #pragma unroll
      for (int r = 0; r < 4; ++r) {
        float v = acc[mf][nf][r] + bv;
        if (OUT_BF16)
          ((unsigned short*)Cout)[(size_t)(row + r) * N + col] = f2bf_bits(v);
        else
          ((float*)Cout)[(size_t)(row + r) * N + col] = v;
      }
    }
  }
}

// ---------------- window attention (unchanged) -----------------------------
__global__ __launch_bounds__(256) void win_attn(
    const unsigned short* __restrict__ qkv,  // [32768, 3072] bf16
    unsigned short* __restrict__ out)        // [32768, 1024] bf16
{
  __shared__ unsigned short Qs[64 * 64];
  __shared__ unsigned short Ks[64 * 64];
  __shared__ unsigned short Vt[64 * 64];
  __shared__ unsigned short Ps[64 * 64];

  const int t    = threadIdx.x;
  const int wave = t >> 6;
  const int lane = t & 63;
  const int wid  = blockIdx.x;          // 0..8191
  const int h    = (wid >> 7) & 15;
  const int b    = wid >> 11;
  const int wi   = wid & 127;
  const int tok0 = b * 8192 + wi * 64;

  const unsigned short* qb = qkv + (size_t)tok0 * 3072 + h * 64;
  const unsigned short* kb = qb + 1024;
  const unsigned short* vb = qb + 2048;

  {
    const int row = t >> 3;
    const int col = (t & 7) << 3;
    unsigned short* Qw = Qs + wave * 512;
    unsigned short* Kw = Ks + wave * 512;
    #pragma unroll
    for (int o = 0; o < 2; ++o) {
      async16(Qw + o * 2048, qb + (size_t)(o * 32 + row) * 3072 + col);
      async16(Kw + o * 2048, kb + (size_t)(o * 32 + row) * 3072 + col);
    }
    const int key = lane;
    const int d0  = wave * 8;
    #pragma unroll
    for (int o = 0; o < 2; ++o) {
      const int d = d0 + o * 32;
      ushort4 r0 = *(const ushort4*)(vb + (size_t)key * 3072 + d);
      ushort4 r1 = *(const ushort4*)(vb + (size_t)key * 3072 + d + 4);
      Vt[(d + 0) * 64 + key] = r0.x; Vt[(d + 1) * 64 + key] = r0.y;
      Vt[(d + 2) * 64 + key] = r0.z; Vt[(d + 3) * 64 + key] = r0.w;
      Vt[(d + 4) * 64 + key] = r1.x; Vt[(d + 5) * 64 + key] = r1.y;
      Vt[(d + 6) * 64 + key] = r1.z; Vt[(d + 7) * 64 + key] = r1.w;
    }
  }
  __syncthreads();

  const int lr = lane & 15;
  const int lq = lane >> 4;

  short8 qa[2];
  #pragma unroll
  for (int k2 = 0; k2 < 2; ++k2)
    qa[k2] = *(const short8*)(Qs + (wave * 16 + lr) * 64 + k2 * 32 + lq * 8);

  float4v s[4];
  #pragma unroll
  for (int jt = 0; jt < 4; ++jt) {
    float4v a = (float4v){0.f, 0.f, 0.f, 0.f};
    #pragma unroll
    for (int k2 = 0; k2 < 2; ++k2) {
      short8 kf = *(const short8*)(Ks + (jt * 16 + lr) * 64 + k2 * 32 + lq * 8);
      a = __builtin_amdgcn_mfma_f32_16x16x32_bf16(qa[k2], kf, a, 0, 0, 0);
    }
    s[jt] = a;
  }

  const float scale = 0.125f;  // 1/sqrt(64)
  float pr[4][4];
  #pragma unroll
  for (int r = 0; r < 4; ++r) {
    float m = s[0][r];
    #pragma unroll
    for (int jt = 1; jt < 4; ++jt) m = fmaxf(m, s[jt][r]);
    #pragma unroll
    for (int off = 1; off < 16; off <<= 1) m = fmaxf(m, __shfl_xor(m, off));
    float sum = 0.f;
    #pragma unroll
    for (int jt = 0; jt < 4; ++jt) {
      float e = __expf((s[jt][r] - m) * scale);
      pr[jt][r] = e; sum += e;
    }
    #pragma unroll
    for (int off = 1; off < 16; off <<= 1) sum += __shfl_xor(sum, off);
    float inv = 1.0f / sum;
    #pragma unroll
    for (int jt = 0; jt < 4; ++jt) pr[jt][r] *= inv;
  }

  #pragma unroll
  for (int jt = 0; jt < 4; ++jt)
    #pragma unroll
    for (int r = 0; r < 4; ++r)
      Ps[(wave * 16 + lq * 4 + r) * 64 + jt * 16 + lr] = f2bf_bits(pr[jt][r]);
  __syncthreads();

  short8 pa[2];
  #pragma unroll
  for (int k2 = 0; k2 < 2; ++k2)
    pa[k2] = *(const short8*)(Ps + (wave * 16 + lr) * 64 + k2 * 32 + lq * 8);

  unsigned short* ob = out + h * 64;
  #pragma unroll
  for (int jd = 0; jd < 4; ++jd) {
    float4v a = (float4v){0.f, 0.f, 0.f, 0.f};
    #pragma unroll
    for (int k2 = 0; k2 < 2; ++k2) {
      short8 vf = *(const short8*)(Vt + (jd * 16 + lr) * 64 + k2 * 32 + lq * 8);
      a = __builtin_amdgcn_mfma_f32_16x16x32_bf16(pa[k2], vf, a, 0, 0, 0);
    }
    #pragma unroll
    for (int r = 0; r < 4; ++r) {
      const int row = wave * 16 + lq * 4 + r;
      ob[(size_t)(tok0 + row) * 1024 + jd * 16 + lr] = f2bf_bits(a[r]);
    }
  }
}

// ---------------- launch ---------------------------------------------------
extern "C" void kernel_launch(void* const* d_in, const int* in_sizes, int n_in,
                              void* d_out, int out_size, void* d_ws, size_t ws_size,
                              hipStream_t stream) {
  const float* x      = (const float*)d_in[0];  // [4,8192,1024]
  const float* w_qkv  = (const float*)d_in[1];  // [3072,1024]
  const float* b_qkv  = (const float*)d_in[2];  // [3072]
  const float* w_proj = (const float*)d_in[3];  // [1024,1024]
  const float* b_proj = (const float*)d_in[4];  // [1024]
  float* outp = (float*)d_out;                  // [4,8192,1024] fp32

  char* ws = (char*)d_ws;
  unsigned short* xb     = (unsigned short*)(ws);
  unsigned short* wqkvb  = (unsigned short*)(ws + 67108864);
  unsigned short* wprojb = (unsigned short*)(ws + 73400320);
  unsigned short* qkvb   = (unsigned short*)(ws + 75497472);
  unsigned short* attnb  = (unsigned short*)(ws + 276824064);

  static int attr_done = 0;
  if (!attr_done) {
    hipFuncSetAttribute(reinterpret_cast<const void*>(&gemm256<true>),
                        hipFuncAttributeMaxDynamicSharedMemorySize, 131072);
    hipFuncSetAttribute(reinterpret_cast<const void*>(&gemm256<false>),
                        hipFuncAttributeMaxDynamicSharedMemorySize, 131072);
    attr_done = 1;
  }

  cast_f32_to_bf16<<<32768, 256, 0, stream>>>(x,      xb,     33554432 / 4);
  cast_f32_to_bf16<<<3072,  256, 0, stream>>>(w_qkv,  wqkvb,  3145728 / 4);
  cast_f32_to_bf16<<<1024,  256, 0, stream>>>(w_proj, wprojb, 1048576 / 4);

  // qkv = x @ w_qkv^T + b_qkv : M=32768, N=3072, K=1024 (mtiles=128, ntiles=12)
  gemm256<true><<<128 * 12, 512, 131072, stream>>>(xb, wqkvb, b_qkv, qkvb,
                                                   32768, 3072, 1024, 12);
  // block-diagonal window attention: 4*16*128 = 8192 windows
  win_attn<<<8192, 256, 0, stream>>>(qkvb, attnb);
  // out = attn @ w_proj^T + b_proj : M=32768, N=1024, K=1024 (ntiles=4)
  gemm256<false><<<128 * 4, 512, 131072, stream>>>(attnb, wprojb, b_proj, outp,
                                                   32768, 1024, 1024, 4);
}

// Round 2
// 588.128 us; speedup vs baseline: 1.1152x; 1.0237x over previous
//
#include <hip/hip_runtime.h>
#include <hip/hip_bf16.h>
#include <cstdint>
#include <cstddef>

// HierarchicalAttention on MI355X (gfx950).
// R4 changes:
//  (a) gemm256 bf16 epilogue: LDS-repack (XOR-swizzled, bank-conflict-free)
//      -> short8 coalesced stores. R1 counters: WRITE_SIZE 344MB vs 201MB
//      ideal = partial-line (32B) store amplification; ~37K cyc/block of
//      epilogue overhead. Plus WAIT_VM(0) after K-loop (drain wrapped DMA
//      before LDS reuse / endpgm).
//  (b) win_attn: 4 windows per block, software-pipelined (issue window i+1
//      Q/K global_load_lds + V reg loads before computing window i; scatter
//      V after PV). O written via wave-private P-strip repack -> short8
//      stores. Was: serial load->sync->compute chain, 16 scalar 2B
//      stores/thread, ~200us for 268MB of traffic.
//
// Workspace layout (total 343,932,928 B):
//   [0)            x_bf16     [32768,1024]  67,108,864 B
//   [67108864)     wqkv_bf16  [3072,1024]    6,291,456 B
//   [73400320)     wproj_bf16 [1024,1024]    2,097,152 B
//   [75497472)     qkv_bf16   [32768,3072] 201,326,592 B
//   [276824064)    attn_bf16  [32768,1024]  67,108,864 B

typedef __attribute__((ext_vector_type(8))) short short8;
typedef __attribute__((ext_vector_type(4))) float float4v;

static __device__ __forceinline__ void async16(void* lds_p, const void* g) {
  __builtin_amdgcn_global_load_lds((const __attribute__((address_space(1))) void*)g,
                                   (__attribute__((address_space(3))) void*)lds_p,
                                   16, 0, 0);
}

static __device__ __forceinline__ unsigned short f2bf_bits(float x) {
  unsigned int u = __float_as_uint(x);
  unsigned int r = (u + 0x7fffu + ((u >> 16) & 1u)) >> 16;  // RNE
  return (unsigned short)r;
}

#define S_BARRIER() asm volatile("s_barrier" ::: "memory")
#define WAIT_VM(n)  asm volatile("s_waitcnt vmcnt(" #n ")" ::: "memory")

// ---------------- cast fp32 -> bf16 (vectorized) ---------------------------
__global__ __launch_bounds__(256) void cast_f32_to_bf16(
    const float* __restrict__ in, unsigned short* __restrict__ out, int n4) {
  int i = blockIdx.x * 256 + threadIdx.x;
  if (i >= n4) return;
  float4 v = ((const float4*)in)[i];
  ushort4 o;
  o.x = f2bf_bits(v.x); o.y = f2bf_bits(v.y);
  o.z = f2bf_bits(v.z); o.w = f2bf_bits(v.w);
  ((ushort4*)out)[i] = o;
}

// ---------------- GEMM: C[M,N] = A[M,K] * B[N,K]^T + bias ------------------
// 256x256 tile, BK=64, 8 waves (2Mx4N), 8-phase counted-vmcnt schedule
// (T1..T5). See R3 comments; schedule unchanged. New: bf16 epilogue repack.
template<bool OUT_BF16>
__global__ __launch_bounds__(512, 2) void gemm256(
    const unsigned short* __restrict__ A,   // [M,K] bf16 bits
    const unsigned short* __restrict__ B,   // [N,K] bf16 bits
    const float* __restrict__ bias,         // [N]
    void* __restrict__ Cout,                // [M,N] bf16 or fp32
    int M, int N, int K, int ntiles)
{
  extern __shared__ unsigned short lds[];
  // elems: A buf0 [0,16384) buf1 [16384,32768); B buf0 [32768,49152) buf1 [49152,65536)

  const int t    = threadIdx.x;             // 0..511
  const int wave = t >> 6;
  const int lane = t & 63;
  const int lr   = lane & 15;
  const int lq   = lane >> 4;
  const int wm   = wave >> 2;               // 0..1
  const int wn   = wave & 3;                // 0..3

  // T1: XCD-chunked swizzle (grid % 8 == 0), then GROUP_M=8 (bm-fast inner)
  const int nwg  = gridDim.x;
  const int q8   = nwg >> 3;
  const int wg   = ((int)blockIdx.x & 7) * q8 + ((int)blockIdx.x >> 3);
  const int GM   = 8;
  const int group = wg / (GM * ntiles);
  const int inG   = wg % (GM * ntiles);
  const int bm    = group * GM + (inG % GM);
  const int bn    = inG / GM;

  const int srow = t >> 3;                            // 0..63 within chunk
  const int sswz = ((t & 7) ^ (srow & 7)) << 3;       // swizzled col (elems)
  const unsigned short* Abase = A + (size_t)(bm * 256 + srow) * K + sswz;
  const unsigned short* Bbase = B + (size_t)(bn * 256 + srow) * K + sswz;
  const int ldsw = wave * 512;

  auto stageA = [&](int kt, int c) {
    async16(lds + (kt & 1) * 16384 + c * 4096 + ldsw,
            Abase + (size_t)(c * 64) * K + kt * 64);
  };
  auto stageB = [&](int kt, int c) {
    async16(lds + 32768 + (kt & 1) * 16384 + c * 4096 + ldsw,
            Bbase + (size_t)(c * 64) * K + kt * 64);
  };

  const int g0 = ((0 + lq) ^ (lr & 7)) << 3;
  const int g1 = ((4 + lq) ^ (lr & 7)) << 3;
  const int arow0 = (wm * 128 + lr) * 64;
  const int brow0 = (wn * 64 + lr) * 64;

  float4v acc[8][4];
  #pragma unroll
  for (int i = 0; i < 8; ++i)
    #pragma unroll
    for (int j = 0; j < 4; ++j) acc[i][j] = (float4v){0.f, 0.f, 0.f, 0.f};

  const int NT = K >> 6;

  #pragma unroll
  for (int c = 0; c < 4; ++c) stageB(0, c);
  #pragma unroll
  for (int c = 0; c < 4; ++c) stageA(0, c);
  #pragma unroll
  for (int c = 0; c < 4; ++c) stageB(1, c);
  WAIT_VM(4);
  S_BARRIER();

  short8 af[4][2], bf[2][2], bf2[2][2];

  for (int kt = 0; kt < NT; ++kt) {
    const int bc = kt & 1;
    int kt1 = kt + 1; if (kt1 == NT) kt1 = 0;         // wrapped stages are
    int kt2 = kt + 2; if (kt2 >= NT) kt2 -= NT;       // harmless (never read)
    const unsigned short* Al = lds + bc * 16384;
    const unsigned short* Bl = lds + 32768 + bc * 16384;

    // ---- phase 0
    #pragma unroll
    for (int mf = 0; mf < 4; ++mf) {
      af[mf][0] = *(const short8*)(Al + arow0 + mf * 1024 + g0);
      af[mf][1] = *(const short8*)(Al + arow0 + mf * 1024 + g1);
    }
    #pragma unroll
    for (int nf = 0; nf < 2; ++nf) {
      bf[nf][0] = *(const short8*)(Bl + brow0 + nf * 1024 + g0);
      bf[nf][1] = *(const short8*)(Bl + brow0 + nf * 1024 + g1);
    }
    stageA(kt1, 0); stageA(kt1, 2);
    S_BARRIER();
    __builtin_amdgcn_s_setprio(1);
    #pragma unroll
    for (int mf = 0; mf < 4; ++mf)
      #pragma unroll
      for (int nf = 0; nf < 2; ++nf) {
        acc[mf][nf] = __builtin_amdgcn_mfma_f32_16x16x32_bf16(af[mf][0], bf[nf][0], acc[mf][nf], 0, 0, 0);
        acc[mf][nf] = __builtin_amdgcn_mfma_f32_16x16x32_bf16(af[mf][1], bf[nf][1], acc[mf][nf], 0, 0, 0);
      }
    __builtin_amdgcn_s_setprio(0);
    S_BARRIER();

    // ---- phase 1
    #pragma unroll
    for (int nf = 0; nf < 2; ++nf) {
      bf2[nf][0] = *(const short8*)(Bl + brow0 + (2 + nf) * 1024 + g0);
      bf2[nf][1] = *(const short8*)(Bl + brow0 + (2 + nf) * 1024 + g1);
    }
    stageA(kt1, 1); stageA(kt1, 3);
    S_BARRIER();
    __builtin_amdgcn_s_setprio(1);
    #pragma unroll
    for (int mf = 0; mf < 4; ++mf)
      #pragma unroll
      for (int nf = 0; nf < 2; ++nf) {
        acc[mf][2 + nf] = __builtin_amdgcn_mfma_f32_16x16x32_bf16(af[mf][0], bf2[nf][0], acc[mf][2 + nf], 0, 0, 0);
        acc[mf][2 + nf] = __builtin_amdgcn_mfma_f32_16x16x32_bf16(af[mf][1], bf2[nf][1], acc[mf][2 + nf], 0, 0, 0);
      }
    __builtin_amdgcn_s_setprio(0);
    S_BARRIER();

    // ---- phase 2
    #pragma unroll
    for (int mf = 0; mf < 4; ++mf) {
      af[mf][0] = *(const short8*)(Al + arow0 + (4 + mf) * 1024 + g0);
      af[mf][1] = *(const short8*)(Al + arow0 + (4 + mf) * 1024 + g1);
    }
    stageB(kt2, 0); stageB(kt2, 1);
    S_BARRIER();
    __builtin_amdgcn_s_setprio(1);
    #pragma unroll
    for (int mf = 0; mf < 4; ++mf)
      #pragma unroll
      for (int nf = 0; nf < 2; ++nf) {
        acc[4 + mf][nf] = __builtin_amdgcn_mfma_f32_16x16x32_bf16(af[mf][0], bf[nf][0], acc[4 + mf][nf], 0, 0, 0);
        acc[4 + mf][nf] = __builtin_amdgcn_mfma_f32_16x16x32_bf16(af[mf][1], bf[nf][1], acc[4 + mf][nf], 0, 0, 0);
      }
    __builtin_amdgcn_s_setprio(0);
    S_BARRIER();

    // ---- phase 3
    stageB(kt2, 2); stageB(kt2, 3);
    WAIT_VM(4);
    S_BARRIER();
    __builtin_amdgcn_s_setprio(1);
    #pragma unroll
    for (int mf = 0; mf < 4; ++mf)
      #pragma unroll
      for (int nf = 0; nf < 2; ++nf) {
        acc[4 + mf][2 + nf] = __builtin_amdgcn_mfma_f32_16x16x32_bf16(af[mf][0], bf2[nf][0], acc[4 + mf][2 + nf], 0, 0, 0);
        acc[4 + mf][2 + nf] = __builtin_amdgcn_mfma_f32_16x16x32_bf16(af[mf][1], bf2[nf][1], acc[4 + mf][2 + nf], 0, 0, 0);
      }
    __builtin_amdgcn_s_setprio(0);
    S_BARRIER();
  }

  WAIT_VM(0);   // drain wrapped DMA stages before LDS reuse / exit

  if (OUT_BF16) {
    // LDS repack: wave-private 64x64 strip in the (drained) A region.
    // Swizzle col' = col ^ (lq<<4); lq == (row>>2)&3 so it's a pure f(row).
    // write banks: (col'>>1)%32 = (nf^lq)*8 + lr>>1 -> 32 banks, 2 lanes each.
    unsigned short* Ost = lds + wave * 4096;
    const int cb = bn * 256 + wn * 64;
    #pragma unroll
    for (int p = 0; p < 2; ++p) {
      #pragma unroll
      for (int nf = 0; nf < 4; ++nf) {
        const float bv = bias[cb + nf * 16 + lr];
        #pragma unroll
        for (int mh = 0; mh < 4; ++mh)
          #pragma unroll
          for (int r = 0; r < 4; ++r) {
            const int row = mh * 16 + lq * 4 + r;
            Ost[row * 64 + ((nf * 16 + lr) ^ (lq << 4))] =
                f2bf_bits(acc[p * 4 + mh][nf][r] + bv);
          }
      }
      #pragma unroll
      for (int k = 0; k < 8; ++k) {
        const int cid = k * 64 + lane;
        const int row = cid >> 3;          // 0..63
        const int c8  = cid & 7;
        const int lqr = (row >> 2) & 3;
        short8 v = *(const short8*)(Ost + row * 64 + ((c8 * 8) ^ (lqr << 4)));
        const size_t grow = (size_t)(bm * 256 + wm * 128 + p * 64 + row);
        *(short8*)((unsigned short*)Cout + grow * N + cb + c8 * 8) = v;
      }
    }
  } else {
    // fp32: 16 lanes x 4B = full 64B line segments already; direct stores.
    const int rbase = bm * 256 + wm * 128 + lq * 4;
    const int cbase = bn * 256 + wn * 64 + lr;
    #pragma unroll
    for (int nf = 0; nf < 4; ++nf) {
      const int col = cbase + nf * 16;
      const float bv = bias[col];
      #pragma unroll
      for (int mf = 0; mf < 8; ++mf) {
        const int row = rbase + mf * 16;
        #pragma unroll
        for (int r = 0; r < 4; ++r)
          ((float*)Cout)[(size_t)(row + r) * N + col] = acc[mf][nf][r] + bv;
      }
    }
  }
}

// ---------------- window attention: 4 windows/block, pipelined -------------
// Per window: Q,K via global_load_lds (dbuf), V reg-staged -> transposed LDS
// (dbuf). Issue window i+1 loads BEFORE computing window i (T14). O goes out
// through the wave's own P-strip (already consumed), XOR-swizzled, as short8.
#define WPB 4

__global__ __launch_bounds__(256) void win_attn(
    const unsigned short* __restrict__ qkv,  // [32768, 3072] bf16
    unsigned short* __restrict__ out)        // [32768, 1024] bf16
{
  __shared__ unsigned short Qs[2][64 * 64];  // 8 KB each buffer
  __shared__ unsigned short Ks[2][64 * 64];
  __shared__ unsigned short Vt[2][64 * 64];  // V transposed: Vt[d][key]
  __shared__ unsigned short Ps[64 * 64];     // P, then per-wave O staging

  const int t    = threadIdx.x;
  const int wave = t >> 6;
  const int lane = t & 63;
  const int lr   = lane & 15;
  const int lq   = lane >> 4;
  const int gbase = blockIdx.x * WPB;

  const int srow = t >> 3;          // 0..31
  const int scol = (t & 7) << 3;

  ushort4 vr[2][2];

  for (int i = -1, c = 0; i < WPB; ++i) {
    // ---- issue loads for window i+1 (prologue: i = -1 issues window 0) ----
    const int nxt = c ^ 1;
    if (i + 1 < WPB) {
      const int g  = gbase + i + 1;
      const int b  = g >> 11, h = (g >> 7) & 15, wi = g & 127;
      const unsigned short* qb =
          qkv + (size_t)(b * 8192 + wi * 64) * 3072 + h * 64;
      const unsigned short* kb = qb + 1024;
      const unsigned short* vb = qb + 2048;
      const int s = (i + 1) & 1;
      unsigned short* Qw = Qs[s] + wave * 512;
      unsigned short* Kw = Ks[s] + wave * 512;
      #pragma unroll
      for (int o = 0; o < 2; ++o) {
        async16(Qw + o * 2048, qb + (size_t)(o * 32 + srow) * 3072 + scol);
        async16(Kw + o * 2048, kb + (size_t)(o * 32 + srow) * 3072 + scol);
      }
      #pragma unroll
      for (int o = 0; o < 2; ++o) {
        const int d = wave * 8 + o * 32;
        vr[o][0] = *(const ushort4*)(vb + (size_t)lane * 3072 + d);
        vr[o][1] = *(const ushort4*)(vb + (size_t)lane * 3072 + d + 4);
      }
    }

    if (i < 0) {
      // prologue: scatter V(0), then barrier (drains async QK(0) too)
      #pragma unroll
      for (int o = 0; o < 2; ++o) {
        const int d = wave * 8 + o * 32;
        unsigned short* V = Vt[0];
        V[(d + 0) * 64 + lane] = vr[o][0].x; V[(d + 1) * 64 + lane] = vr[o][0].y;
        V[(d + 2) * 64 + lane] = vr[o][0].z; V[(d + 3) * 64 + lane] = vr[o][0].w;
        V[(d + 4) * 64 + lane] = vr[o][1].x; V[(d + 5) * 64 + lane] = vr[o][1].y;
        V[(d + 6) * 64 + lane] = vr[o][1].z; V[(d + 7) * 64 + lane] = vr[o][1].w;
      }
      __syncthreads();
      continue;
    }

    // ---- compute window i from buffers [c] --------------------------------
    const int g  = gbase + i;
    const int b  = g >> 11, h = (g >> 7) & 15, wi = g & 127;
    const int tok0 = b * 8192 + wi * 64;

    // S = Q K^T
    short8 qa[2];
    #pragma unroll
    for (int k2 = 0; k2 < 2; ++k2)
      qa[k2] = *(const short8*)(Qs[c] + (wave * 16 + lr) * 64 + k2 * 32 + lq * 8);

    float4v s4[4];
    #pragma unroll
    for (int jt = 0; jt < 4; ++jt) {
      float4v a = (float4v){0.f, 0.f, 0.f, 0.f};
      #pragma unroll
      for (int k2 = 0; k2 < 2; ++k2) {
        short8 kf = *(const short8*)(Ks[c] + (jt * 16 + lr) * 64 + k2 * 32 + lq * 8);
        a = __builtin_amdgcn_mfma_f32_16x16x32_bf16(qa[k2], kf, a, 0, 0, 0);
      }
      s4[jt] = a;
    }

    const float scale = 0.125f;  // 1/sqrt(64)
    float pr[4][4];
    #pragma unroll
    for (int r = 0; r < 4; ++r) {
      float m = s4[0][r];
      #pragma unroll
      for (int jt = 1; jt < 4; ++jt) m = fmaxf(m, s4[jt][r]);
      #pragma unroll
      for (int off = 1; off < 16; off <<= 1) m = fmaxf(m, __shfl_xor(m, off));
      float sum = 0.f;
      #pragma unroll
      for (int jt = 0; jt < 4; ++jt) {
        float e = __expf((s4[jt][r] - m) * scale);
        pr[jt][r] = e; sum += e;
      }
      #pragma unroll
      for (int off = 1; off < 16; off <<= 1) sum += __shfl_xor(sum, off);
      float inv = 1.0f / sum;
      #pragma unroll
      for (int jt = 0; jt < 4; ++jt) pr[jt][r] *= inv;
    }

    #pragma unroll
    for (int jt = 0; jt < 4; ++jt)
      #pragma unroll
      for (int r = 0; r < 4; ++r)
        Ps[(wave * 16 + lq * 4 + r) * 64 + jt * 16 + lr] = f2bf_bits(pr[jt][r]);
    __syncthreads();   // (A) P visible; also drains next-window async QK

    // O = P V  (reads only this wave's 16-row P strip + Vt[c])
    short8 pa[2];
    #pragma unroll
    for (int k2 = 0; k2 < 2; ++k2)
      pa[k2] = *(const short8*)(Ps + (wave * 16 + lr) * 64 + k2 * 32 + lq * 8);

    float4v o4[4];
    #pragma unroll
    for (int jd = 0; jd < 4; ++jd) {
      float4v a = (float4v){0.f, 0.f, 0.f, 0.f};
      #pragma unroll
      for (int k2 = 0; k2 < 2; ++k2) {
        short8 vf = *(const short8*)(Vt[c] + (jd * 16 + lr) * 64 + k2 * 32 + lq * 8);
        a = __builtin_amdgcn_mfma_f32_16x16x32_bf16(pa[k2], vf, a, 0, 0, 0);
      }
      o4[jd] = a;
    }

    // O out via wave-private P strip (consumed above), swizzled, short8 store
    unsigned short* Ost = Ps + wave * 1024;   // 16 rows x 64 cols
    #pragma unroll
    for (int jd = 0; jd < 4; ++jd)
      #pragma unroll
      for (int r = 0; r < 4; ++r)
        Ost[(lq * 4 + r) * 64 + ((jd * 16 + lr) ^ (lq << 4))] =
            f2bf_bits(o4[jd][r]);
    #pragma unroll
    for (int k = 0; k < 2; ++k) {
      const int cid = k * 64 + lane;
      const int row = cid >> 3;          // 0..15
      const int c8  = cid & 7;
      const int lqr = (row >> 2) & 3;
      short8 v = *(const short8*)(Ost + row * 64 + ((c8 * 8) ^ (lqr << 4)));
      *(short8*)(out + (size_t)(tok0 + wave * 16 + row) * 1024 + h * 64 + c8 * 8) = v;
    }

    // scatter V(i+1) into Vt[nxt] (prior readers of Vt[nxt] finished at (B)
    // of iteration i-1; compiler waits the vr loads)
    if (i + 1 < WPB) {
      #pragma unroll
      for (int o = 0; o < 2; ++o) {
        const int d = wave * 8 + o * 32;
        unsigned short* V = Vt[nxt];
        V[(d + 0) * 64 + lane] = vr[o][0].x; V[(d + 1) * 64 + lane] = vr[o][0].y;
        V[(d + 2) * 64 + lane] = vr[o][0].z; V[(d + 3) * 64 + lane] = vr[o][0].w;
        V[(d + 4) * 64 + lane] = vr[o][1].x; V[(d + 5) * 64 + lane] = vr[o][1].y;
        V[(d + 6) * 64 + lane] = vr[o][1].z; V[(d + 7) * 64 + lane] = vr[o][1].w;
      }
    }
    __syncthreads();   // (B) P strip free; Vt[nxt] visible; QK(i+1) landed
    c ^= 1;
  }
}

// ---------------- launch ---------------------------------------------------
extern "C" void kernel_launch(void* const* d_in, const int* in_sizes, int n_in,
                              void* d_out, int out_size, void* d_ws, size_t ws_size,
                              hipStream_t stream) {
  const float* x      = (const float*)d_in[0];  // [4,8192,1024]
  const float* w_qkv  = (const float*)d_in[1];  // [3072,1024]
  const float* b_qkv  = (const float*)d_in[2];  // [3072]
  const float* w_proj = (const float*)d_in[3];  // [1024,1024]
  const float* b_proj = (const float*)d_in[4];  // [1024]
  float* outp = (float*)d_out;                  // [4,8192,1024] fp32

  char* ws = (char*)d_ws;
  unsigned short* xb     = (unsigned short*)(ws);
  unsigned short* wqkvb  = (unsigned short*)(ws + 67108864);
  unsigned short* wprojb = (unsigned short*)(ws + 73400320);
  unsigned short* qkvb   = (unsigned short*)(ws + 75497472);
  unsigned short* attnb  = (unsigned short*)(ws + 276824064);

  static int attr_done = 0;
  if (!attr_done) {
    hipFuncSetAttribute(reinterpret_cast<const void*>(&gemm256<true>),
                        hipFuncAttributeMaxDynamicSharedMemorySize, 131072);
    hipFuncSetAttribute(reinterpret_cast<const void*>(&gemm256<false>),
                        hipFuncAttributeMaxDynamicSharedMemorySize, 131072);
    attr_done = 1;
  }

  cast_f32_to_bf16<<<32768, 256, 0, stream>>>(x,      xb,     33554432 / 4);
  cast_f32_to_bf16<<<3072,  256, 0, stream>>>(w_qkv,  wqkvb,  3145728 / 4);
  cast_f32_to_bf16<<<1024,  256, 0, stream>>>(w_proj, wprojb, 1048576 / 4);

  // qkv = x @ w_qkv^T + b_qkv : M=32768, N=3072, K=1024 (mtiles=128, ntiles=12)
  gemm256<true><<<128 * 12, 512, 131072, stream>>>(xb, wqkvb, b_qkv, qkvb,
                                                   32768, 3072, 1024, 12);
  // block-diagonal window attention: 8192 windows, 4 per block
  win_attn<<<8192 / WPB, 256, 0, stream>>>(qkvb, attnb);
  // out = attn @ w_proj^T + b_proj : M=32768, N=1024, K=1024 (ntiles=4)
  gemm256<false><<<128 * 4, 512, 131072, stream>>>(attnb, wprojb, b_proj, outp,
                                                   32768, 1024, 1024, 4);
}

// Round 3
// 580.002 us; speedup vs baseline: 1.1309x; 1.0140x over previous
//
#include <hip/hip_runtime.h>
#include <hip/hip_bf16.h>
#include <cstdint>
#include <cstddef>

// HierarchicalAttention on MI355X (gfx950).
// R5 change: win_attn rebuilt with counted-vmcnt discipline (R4's version used
// __syncthreads => vmcnt(0) drain mid-window, killing its own pipeline, and
// 56KB LDS => 2 blocks/CU). New structure: Q->regs, K->swizzled LDS via
// global_load_lds (dbuf), V->regs->swizzled transposed LDS (dbuf), P in
// wave-private strip; ONE raw s_barrier per window with lgkmcnt(0)+vmcnt(2)
// (K-DMA drained, Q/O stay in flight). All LDS b128 reads 16B-unit XOR
// swizzled (old [64][64] row-major reads were 16-way bank conflicts).
// LDS 40KB, __launch_bounds__(256,4) -> 4 blocks/CU, grid 1024 resident.
// gemm256 unchanged from R4 (209us qkv, WRITE_SIZE at ideal).
//
// Workspace layout (total 343,932,928 B):
//   [0)            x_bf16     [32768,1024]  67,108,864 B
//   [67108864)     wqkv_bf16  [3072,1024]    6,291,456 B
//   [73400320)     wproj_bf16 [1024,1024]    2,097,152 B
//   [75497472)     qkv_bf16   [32768,3072] 201,326,592 B
//   [276824064)    attn_bf16  [32768,1024]  67,108,864 B

typedef __attribute__((ext_vector_type(8))) short short8;
typedef __attribute__((ext_vector_type(4))) float float4v;

static __device__ __forceinline__ void async16(void* lds_p, const void* g) {
  __builtin_amdgcn_global_load_lds((const __attribute__((address_space(1))) void*)g,
                                   (__attribute__((address_space(3))) void*)lds_p,
                                   16, 0, 0);
}

static __device__ __forceinline__ unsigned short f2bf_bits(float x) {
  unsigned int u = __float_as_uint(x);
  unsigned int r = (u + 0x7fffu + ((u >> 16) & 1u)) >> 16;  // RNE
  return (unsigned short)r;
}

#define S_BARRIER() asm volatile("s_barrier" ::: "memory")
#define WAIT_VM(n)  asm volatile("s_waitcnt vmcnt(" #n ")" ::: "memory")
#define WAIT_LGKM0() asm volatile("s_waitcnt lgkmcnt(0)" ::: "memory")

// ---------------- cast fp32 -> bf16 (vectorized) ---------------------------
__global__ __launch_bounds__(256) void cast_f32_to_bf16(
    const float* __restrict__ in, unsigned short* __restrict__ out, int n4) {
  int i = blockIdx.x * 256 + threadIdx.x;
  if (i >= n4) return;
  float4 v = ((const float4*)in)[i];
  ushort4 o;
  o.x = f2bf_bits(v.x); o.y = f2bf_bits(v.y);
  o.z = f2bf_bits(v.z); o.w = f2bf_bits(v.w);
  ((ushort4*)out)[i] = o;
}

// ---------------- GEMM: C[M,N] = A[M,K] * B[N,K]^T + bias ------------------
// 256x256 tile, BK=64, 8 waves (2Mx4N), 8-phase counted-vmcnt schedule
// (T1..T5) + bf16 LDS-repack epilogue. Unchanged from R4.
template<bool OUT_BF16>
__global__ __launch_bounds__(512, 2) void gemm256(
    const unsigned short* __restrict__ A,   // [M,K] bf16 bits
    const unsigned short* __restrict__ B,   // [N,K] bf16 bits
    const float* __restrict__ bias,         // [N]
    void* __restrict__ Cout,                // [M,N] bf16 or fp32
    int M, int N, int K, int ntiles)
{
  extern __shared__ unsigned short lds[];

  const int t    = threadIdx.x;             // 0..511
  const int wave = t >> 6;
  const int lane = t & 63;
  const int lr   = lane & 15;
  const int lq   = lane >> 4;
  const int wm   = wave >> 2;               // 0..1
  const int wn   = wave & 3;                // 0..3

  const int nwg  = gridDim.x;
  const int q8   = nwg >> 3;
  const int wg   = ((int)blockIdx.x & 7) * q8 + ((int)blockIdx.x >> 3);
  const int GM   = 8;
  const int group = wg / (GM * ntiles);
  const int inG   = wg % (GM * ntiles);
  const int bm    = group * GM + (inG % GM);
  const int bn    = inG / GM;

  const int srow = t >> 3;                            // 0..63 within chunk
  const int sswz = ((t & 7) ^ (srow & 7)) << 3;       // swizzled col (elems)
  const unsigned short* Abase = A + (size_t)(bm * 256 + srow) * K + sswz;
  const unsigned short* Bbase = B + (size_t)(bn * 256 + srow) * K + sswz;
  const int ldsw = wave * 512;

  auto stageA = [&](int kt, int c) {
    async16(lds + (kt & 1) * 16384 + c * 4096 + ldsw,
            Abase + (size_t)(c * 64) * K + kt * 64);
  };
  auto stageB = [&](int kt, int c) {
    async16(lds + 32768 + (kt & 1) * 16384 + c * 4096 + ldsw,
            Bbase + (size_t)(c * 64) * K + kt * 64);
  };

  const int g0 = ((0 + lq) ^ (lr & 7)) << 3;
  const int g1 = ((4 + lq) ^ (lr & 7)) << 3;
  const int arow0 = (wm * 128 + lr) * 64;
  const int brow0 = (wn * 64 + lr) * 64;

  float4v acc[8][4];
  #pragma unroll
  for (int i = 0; i < 8; ++i)
    #pragma unroll
    for (int j = 0; j < 4; ++j) acc[i][j] = (float4v){0.f, 0.f, 0.f, 0.f};

  const int NT = K >> 6;

  #pragma unroll
  for (int c = 0; c < 4; ++c) stageB(0, c);
  #pragma unroll
  for (int c = 0; c < 4; ++c) stageA(0, c);
  #pragma unroll
  for (int c = 0; c < 4; ++c) stageB(1, c);
  WAIT_VM(4);
  S_BARRIER();

  short8 af[4][2], bf[2][2], bf2[2][2];

  for (int kt = 0; kt < NT; ++kt) {
    const int bc = kt & 1;
    int kt1 = kt + 1; if (kt1 == NT) kt1 = 0;
    int kt2 = kt + 2; if (kt2 >= NT) kt2 -= NT;
    const unsigned short* Al = lds + bc * 16384;
    const unsigned short* Bl = lds + 32768 + bc * 16384;

    // ---- phase 0
    #pragma unroll
    for (int mf = 0; mf < 4; ++mf) {
      af[mf][0] = *(const short8*)(Al + arow0 + mf * 1024 + g0);
      af[mf][1] = *(const short8*)(Al + arow0 + mf * 1024 + g1);
    }
    #pragma unroll
    for (int nf = 0; nf < 2; ++nf) {
      bf[nf][0] = *(const short8*)(Bl + brow0 + nf * 1024 + g0);
      bf[nf][1] = *(const short8*)(Bl + brow0 + nf * 1024 + g1);
    }
    stageA(kt1, 0); stageA(kt1, 2);
    S_BARRIER();
    __builtin_amdgcn_s_setprio(1);
    #pragma unroll
    for (int mf = 0; mf < 4; ++mf)
      #pragma unroll
      for (int nf = 0; nf < 2; ++nf) {
        acc[mf][nf] = __builtin_amdgcn_mfma_f32_16x16x32_bf16(af[mf][0], bf[nf][0], acc[mf][nf], 0, 0, 0);
        acc[mf][nf] = __builtin_amdgcn_mfma_f32_16x16x32_bf16(af[mf][1], bf[nf][1], acc[mf][nf], 0, 0, 0);
      }
    __builtin_amdgcn_s_setprio(0);
    S_BARRIER();

    // ---- phase 1
    #pragma unroll
    for (int nf = 0; nf < 2; ++nf) {
      bf2[nf][0] = *(const short8*)(Bl + brow0 + (2 + nf) * 1024 + g0);
      bf2[nf][1] = *(const short8*)(Bl + brow0 + (2 + nf) * 1024 + g1);
    }
    stageA(kt1, 1); stageA(kt1, 3);
    S_BARRIER();
    __builtin_amdgcn_s_setprio(1);
    #pragma unroll
    for (int mf = 0; mf < 4; ++mf)
      #pragma unroll
      for (int nf = 0; nf < 2; ++nf) {
        acc[mf][2 + nf] = __builtin_amdgcn_mfma_f32_16x16x32_bf16(af[mf][0], bf2[nf][0], acc[mf][2 + nf], 0, 0, 0);
        acc[mf][2 + nf] = __builtin_amdgcn_mfma_f32_16x16x32_bf16(af[mf][1], bf2[nf][1], acc[mf][2 + nf], 0, 0, 0);
      }
    __builtin_amdgcn_s_setprio(0);
    S_BARRIER();

    // ---- phase 2
    #pragma unroll
    for (int mf = 0; mf < 4; ++mf) {
      af[mf][0] = *(const short8*)(Al + arow0 + (4 + mf) * 1024 + g0);
      af[mf][1] = *(const short8*)(Al + arow0 + (4 + mf) * 1024 + g1);
    }
    stageB(kt2, 0); stageB(kt2, 1);
    S_BARRIER();
    __builtin_amdgcn_s_setprio(1);
    #pragma unroll
    for (int mf = 0; mf < 4; ++mf)
      #pragma unroll
      for (int nf = 0; nf < 2; ++nf) {
        acc[4 + mf][nf] = __builtin_amdgcn_mfma_f32_16x16x32_bf16(af[mf][0], bf[nf][0], acc[4 + mf][nf], 0, 0, 0);
        acc[4 + mf][nf] = __builtin_amdgcn_mfma_f32_16x16x32_bf16(af[mf][1], bf[nf][1], acc[4 + mf][nf], 0, 0, 0);
      }
    __builtin_amdgcn_s_setprio(0);
    S_BARRIER();

    // ---- phase 3
    stageB(kt2, 2); stageB(kt2, 3);
    WAIT_VM(4);
    S_BARRIER();
    __builtin_amdgcn_s_setprio(1);
    #pragma unroll
    for (int mf = 0; mf < 4; ++mf)
      #pragma unroll
      for (int nf = 0; nf < 2; ++nf) {
        acc[4 + mf][2 + nf] = __builtin_amdgcn_mfma_f32_16x16x32_bf16(af[mf][0], bf2[nf][0], acc[4 + mf][2 + nf], 0, 0, 0);
        acc[4 + mf][2 + nf] = __builtin_amdgcn_mfma_f32_16x16x32_bf16(af[mf][1], bf2[nf][1], acc[4 + mf][2 + nf], 0, 0, 0);
      }
    __builtin_amdgcn_s_setprio(0);
    S_BARRIER();
  }

  WAIT_VM(0);   // drain wrapped DMA stages before LDS reuse / exit

  if (OUT_BF16) {
    unsigned short* Ost = lds + wave * 4096;
    const int cb = bn * 256 + wn * 64;
    #pragma unroll
    for (int p = 0; p < 2; ++p) {
      #pragma unroll
      for (int nf = 0; nf < 4; ++nf) {
        const float bv = bias[cb + nf * 16 + lr];
        #pragma unroll
        for (int mh = 0; mh < 4; ++mh)
          #pragma unroll
          for (int r = 0; r < 4; ++r) {
            const int row = mh * 16 + lq * 4 + r;
            Ost[row * 64 + ((nf * 16 + lr) ^ (lq << 4))] =
                f2bf_bits(acc[p * 4 + mh][nf][r] + bv);
          }
      }
      #pragma unroll
      for (int k = 0; k < 8; ++k) {
        const int cid = k * 64 + lane;
        const int row = cid >> 3;          // 0..63
        const int c8  = cid & 7;
        const int lqr = (row >> 2) & 3;
        short8 v = *(const short8*)(Ost + row * 64 + ((c8 * 8) ^ (lqr << 4)));
        const size_t grow = (size_t)(bm * 256 + wm * 128 + p * 64 + row);
        *(short8*)((unsigned short*)Cout + grow * N + cb + c8 * 8) = v;
      }
    }
  } else {
    const int rbase = bm * 256 + wm * 128 + lq * 4;
    const int cbase = bn * 256 + wn * 64 + lr;
    #pragma unroll
    for (int nf = 0; nf < 4; ++nf) {
      const int col = cbase + nf * 16;
      const float bv = bias[col];
      #pragma unroll
      for (int mf = 0; mf < 8; ++mf) {
        const int row = rbase + mf * 16;
        #pragma unroll
        for (int r = 0; r < 4; ++r)
          ((float*)Cout)[(size_t)(row + r) * N + col] = acc[mf][nf][r] + bv;
      }
    }
  }
}

// ---------------- window attention: 8 windows/block, counted-vmcnt ---------
// Per window: Q -> regs (2x short8/lane); K -> Ks[dbuf] via global_load_lds
// (source pre-swizzled, 16B-unit c8'=c8^(row&7)); V -> regs -> Vt[dbuf]
// scatter (swizzled); P/O through wave-private 16x64 strip. One s_barrier
// per window, preceded by lgkmcnt(0) + vmcnt(2) (drain own K-DMA only; Q
// loads + O stores stay in flight).
#define WPB 8

__global__ __launch_bounds__(256, 4) void win_attn(
    const unsigned short* __restrict__ qkv,  // [32768, 3072] bf16
    unsigned short* __restrict__ out)        // [32768, 1024] bf16
{
  __shared__ unsigned short Ks[2][64 * 64];  // 8 KB per buffer, swizzled
  __shared__ unsigned short Vt[2][64 * 64];  // V^T, swizzled
  __shared__ unsigned short Ps[4 * 16 * 64]; // per-wave private strips

  const int t    = threadIdx.x;
  const int wave = t >> 6;
  const int lane = t & 63;
  const int lr   = lane & 15;
  const int lq   = lane >> 4;
  const int k7   = lane & 7;
  const int kh   = lane >> 3;                 // 0..7
  const int kswz = (k7 ^ kh) << 3;            // source col pre-swizzle (elems)
  const int gbase = blockIdx.x * WPB;
  unsigned short* Pst = Ps + wave * 1024;

  short8 qa[2], vr[2];

  auto qptr = [&](int g) {
    const int b = g >> 11, h = (g >> 7) & 15, wi = g & 127;
    return qkv + (size_t)(b * 8192 + wi * 64) * 3072 + h * 64;
  };
  auto stageK = [&](int s, const unsigned short* kb) {
    // wave stages rows [wave*16, wave*16+16); LDS linear, global pre-swizzled
    #pragma unroll
    for (int o = 0; o < 2; ++o)
      async16(&Ks[s][(wave * 16 + o * 8) * 64],
              kb + (size_t)(wave * 16 + o * 8 + kh) * 3072 + kswz);
  };
  auto loadV = [&](const unsigned short* vb) {
    #pragma unroll
    for (int o = 0; o < 2; ++o)
      vr[o] = *(const short8*)(vb + (size_t)lane * 3072 + wave * 8 + o * 32);
  };
  auto loadQ = [&](const unsigned short* qb) {
    #pragma unroll
    for (int k2 = 0; k2 < 2; ++k2)
      qa[k2] = *(const short8*)(qb + (size_t)(wave * 16 + lr) * 3072 + k2 * 32 + lq * 8);
  };
  auto scatterV = [&](int s) {
    // vr[o][j] = V[key=lane][d+j], d = wave*8+o*32; slot col 16B-unit ^ (d&7)
    #pragma unroll
    for (int o = 0; o < 2; ++o) {
      const int d = wave * 8 + o * 32;
      #pragma unroll
      for (int j = 0; j < 8; ++j)
        Vt[s][(d + j) * 64 + k7 + ((kh ^ j) << 3)] = vr[o][j];
    }
  };

  // prologue: stage window 0 (V first, then K-DMA, then Q)
  {
    const unsigned short* qb0 = qptr(gbase);
    loadV(qb0 + 2048);
    stageK(0, qb0 + 1024);
    loadQ(qb0);
    scatterV(0);     // waits V loads (vmcnt leaves K-DMA + Q in flight)
    WAIT_VM(2);      // drain own K-DMA (Q stays)
    WAIT_LGKM0();    // Vt writes visible
    S_BARRIER();
  }

  for (int i = 0; i < WPB; ++i) {
    const int c = i & 1;
    const int g = gbase + i;
    const int h = (g >> 7) & 15;
    const int tok0 = ((g >> 11) * 8192) + (g & 127) * 64;
    const bool more = (i + 1 < WPB);
    const unsigned short* qb1 = qptr(more ? g + 1 : g);

    if (more) { loadV(qb1 + 2048); stageK(c ^ 1, qb1 + 1024); }

    // S = Q K^T  (K read un-swizzled: unit (k2*4+lq) ^ (row&7), row&7 = lr&7)
    float4v s4[4];
    #pragma unroll
    for (int jt = 0; jt < 4; ++jt) {
      float4v a = (float4v){0.f, 0.f, 0.f, 0.f};
      #pragma unroll
      for (int k2 = 0; k2 < 2; ++k2) {
        short8 kf = *(const short8*)(&Ks[c][(jt * 16 + lr) * 64 +
                                            (((k2 * 4 + lq) ^ (lr & 7)) << 3)]);
        a = __builtin_amdgcn_mfma_f32_16x16x32_bf16(qa[k2], kf, a, 0, 0, 0);
      }
      s4[jt] = a;
    }

    if (more) loadQ(qb1);   // qa dead after QK; overlaps softmax/PV latency

    // softmax (rows spread over lq*4+r; cols over jt x lr, 16-lane groups)
    const float scale = 0.125f;  // 1/sqrt(64)
    float pr[4][4];
    #pragma unroll
    for (int r = 0; r < 4; ++r) {
      float m = s4[0][r];
      #pragma unroll
      for (int jt = 1; jt < 4; ++jt) m = fmaxf(m, s4[jt][r]);
      #pragma unroll
      for (int off = 1; off < 16; off <<= 1) m = fmaxf(m, __shfl_xor(m, off));
      float sum = 0.f;
      #pragma unroll
      for (int jt = 0; jt < 4; ++jt) {
        float e = __expf((s4[jt][r] - m) * scale);
        pr[jt][r] = e; sum += e;
      }
      #pragma unroll
      for (int off = 1; off < 16; off <<= 1) sum += __shfl_xor(sum, off);
      float inv = 1.0f / sum;
      #pragma unroll
      for (int jt = 0; jt < 4; ++jt) pr[jt][r] *= inv;
    }

    // P -> wave-private strip (16B-unit swizzle c8' = c8 ^ (row&7))
    #pragma unroll
    for (int jt = 0; jt < 4; ++jt)
      #pragma unroll
      for (int r = 0; r < 4; ++r) {
        const int row = lq * 4 + r;
        const int cu  = (jt * 2 + (lr >> 3)) ^ (row & 7);
        Pst[row * 64 + (cu << 3) + (lr & 7)] = f2bf_bits(pr[jt][r]);
      }
    short8 pa[2];
    #pragma unroll
    for (int k2 = 0; k2 < 2; ++k2)
      pa[k2] = *(const short8*)(&Pst[lr * 64 + (((k2 * 4 + lq) ^ (lr & 7)) << 3)]);

    // O = P V
    float4v o4[4];
    #pragma unroll
    for (int jd = 0; jd < 4; ++jd) {
      float4v a = (float4v){0.f, 0.f, 0.f, 0.f};
      #pragma unroll
      for (int k2 = 0; k2 < 2; ++k2) {
        short8 vf = *(const short8*)(&Vt[c][(jd * 16 + lr) * 64 +
                                            (((k2 * 4 + lq) ^ (lr & 7)) << 3)]);
        a = __builtin_amdgcn_mfma_f32_16x16x32_bf16(pa[k2], vf, a, 0, 0, 0);
      }
      o4[jd] = a;
    }

    if (more) scatterV(c ^ 1);  // waits vr (K-DMA + Q still in flight)

    // O out via wave-private strip repack (R4-verified), short8 stores
    #pragma unroll
    for (int jd = 0; jd < 4; ++jd)
      #pragma unroll
      for (int r = 0; r < 4; ++r)
        Pst[(lq * 4 + r) * 64 + ((jd * 16 + lr) ^ (lq << 4))] = f2bf_bits(o4[jd][r]);
    #pragma unroll
    for (int k = 0; k < 2; ++k) {
      const int cid = k * 64 + lane;
      const int row = cid >> 3;          // 0..15
      const int c8  = cid & 7;
      const int lqr = (row >> 2) & 3;
      short8 v = *(const short8*)(&Pst[row * 64 + ((c8 * 8) ^ (lqr << 4))]);
      *(short8*)(out + (size_t)(tok0 + wave * 16 + row) * 1024 + h * 64 + c8 * 8) = v;
    }

    if (more) {
      WAIT_VM(2);     // drain own K-DMA (oldest); Q loads + O stores in flight
      WAIT_LGKM0();   // Vt[c^1] writes visible to other waves
      S_BARRIER();
    }
  }
}

// ---------------- launch ---------------------------------------------------
extern "C" void kernel_launch(void* const* d_in, const int* in_sizes, int n_in,
                              void* d_out, int out_size, void* d_ws, size_t ws_size,
                              hipStream_t stream) {
  const float* x      = (const float*)d_in[0];  // [4,8192,1024]
  const float* w_qkv  = (const float*)d_in[1];  // [3072,1024]
  const float* b_qkv  = (const float*)d_in[2];  // [3072]
  const float* w_proj = (const float*)d_in[3];  // [1024,1024]
  const float* b_proj = (const float*)d_in[4];  // [1024]
  float* outp = (float*)d_out;                  // [4,8192,1024] fp32

  char* ws = (char*)d_ws;
  unsigned short* xb     = (unsigned short*)(ws);
  unsigned short* wqkvb  = (unsigned short*)(ws + 67108864);
  unsigned short* wprojb = (unsigned short*)(ws + 73400320);
  unsigned short* qkvb   = (unsigned short*)(ws + 75497472);
  unsigned short* attnb  = (unsigned short*)(ws + 276824064);

  static int attr_done = 0;
  if (!attr_done) {
    hipFuncSetAttribute(reinterpret_cast<const void*>(&gemm256<true>),
                        hipFuncAttributeMaxDynamicSharedMemorySize, 131072);
    hipFuncSetAttribute(reinterpret_cast<const void*>(&gemm256<false>),
                        hipFuncAttributeMaxDynamicSharedMemorySize, 131072);
    attr_done = 1;
  }

  cast_f32_to_bf16<<<32768, 256, 0, stream>>>(x,      xb,     33554432 / 4);
  cast_f32_to_bf16<<<3072,  256, 0, stream>>>(w_qkv,  wqkvb,  3145728 / 4);
  cast_f32_to_bf16<<<1024,  256, 0, stream>>>(w_proj, wprojb, 1048576 / 4);

  // qkv = x @ w_qkv^T + b_qkv : M=32768, N=3072, K=1024 (mtiles=128, ntiles=12)
  gemm256<true><<<128 * 12, 512, 131072, stream>>>(xb, wqkvb, b_qkv, qkvb,
                                                   32768, 3072, 1024, 12);
  // block-diagonal window attention: 8192 windows, 8 per block
  win_attn<<<8192 / WPB, 256, 0, stream>>>(qkvb, attnb);
  // out = attn @ w_proj^T + b_proj : M=32768, N=1024, K=1024 (ntiles=4)
  gemm256<false><<<128 * 4, 512, 131072, stream>>>(attnb, wprojb, b_proj, outp,
                                                   32768, 1024, 1024, 4);
}